// Round 1
// baseline (50.439 us; speedup 1.0000x reference)
//
#include <hip/hip_runtime.h>

#define FF 7
#define PIX_PER_THREAD 4
#define BLOCK 256

__global__ __launch_bounds__(BLOCK) void fused_scale_matmul_kernel(
    const float* __restrict__ x,   // [npix * 7]
    const float* __restrict__ d,   // [npix]
    const float* __restrict__ W,   // [7 * 7]
    float* __restrict__ out,       // [npix * 7]
    int npix)
{
    // W: uniform address -> scalar (SGPR) loads, broadcast to all lanes.
    float w[FF][FF];
#pragma unroll
    for (int f = 0; f < FF; ++f)
#pragma unroll
        for (int g = 0; g < FF; ++g)
            w[f][g] = W[f * FF + g];

    int t = blockIdx.x * blockDim.x + threadIdx.x;
    long long p0 = (long long)t * PIX_PER_THREAD;
    if (p0 >= npix) return;  // grid sized exactly; npix % 4 == 0

    // 4 pixels * 7 floats = 28 floats = 7 float4 (112 B, 16B-aligned).
    float4 xv[7];
    const float4* xp = reinterpret_cast<const float4*>(x + p0 * FF);
#pragma unroll
    for (int k = 0; k < 7; ++k) xv[k] = xp[k];

    float4 dv = *reinterpret_cast<const float4*>(d + p0);
    float dd[PIX_PER_THREAD] = {dv.x, dv.y, dv.z, dv.w};

    const float* xs = reinterpret_cast<const float*>(xv);
    float ov[PIX_PER_THREAD * FF];
#pragma unroll
    for (int p = 0; p < PIX_PER_THREAD; ++p) {
#pragma unroll
        for (int g = 0; g < FF; ++g) {
            float acc = 0.0f;
#pragma unroll
            for (int f = 0; f < FF; ++f)
                acc = fmaf(xs[p * FF + f], w[f][g], acc);
            ov[p * FF + g] = dd[p] * acc;
        }
    }

    float4* op = reinterpret_cast<float4*>(out + p0 * FF);
    const float4* os = reinterpret_cast<const float4*>(ov);
#pragma unroll
    for (int k = 0; k < 7; ++k) op[k] = os[k];
}

extern "C" void kernel_launch(void* const* d_in, const int* in_sizes, int n_in,
                              void* d_out, int out_size, void* d_ws, size_t ws_size,
                              hipStream_t stream) {
    const float* x = (const float*)d_in[0];
    const float* d = (const float*)d_in[1];
    const float* W = (const float*)d_in[2];
    float* out = (float*)d_out;

    int npix = in_sizes[1];  // H * W = 2048 * 2048
    int nthreads = npix / PIX_PER_THREAD;
    int nblocks = (nthreads + BLOCK - 1) / BLOCK;

    hipLaunchKernelGGL(fused_scale_matmul_kernel,
                       dim3(nblocks), dim3(BLOCK), 0, stream,
                       x, d, W, out, npix);
}